// Round 25
// baseline (99.644 us; speedup 1.0000x reference)
//
#include <hip/hip_runtime.h>
#include <hip/hip_bf16.h>

typedef _Float16 f16x8 __attribute__((ext_vector_type(8)));
typedef _Float16 f16x2 __attribute__((ext_vector_type(2)));
typedef float f32x4 __attribute__((ext_vector_type(4)));
typedef float f32x16 __attribute__((ext_vector_type(16)));
typedef unsigned int u32x2 __attribute__((ext_vector_type(2)));
typedef unsigned int u32x4 __attribute__((ext_vector_type(4)));
typedef unsigned short us8 __attribute__((ext_vector_type(8)));

#define GLDS16(gp, lp)                                                        \
  __builtin_amdgcn_global_load_lds(                                           \
      (const __attribute__((address_space(1))) void*)(gp),                    \
      (__attribute__((address_space(3))) void*)(lp), 16, 0, 0)

#define MEMFENCE asm volatile("" ::: "memory")

__device__ __forceinline__ unsigned short f2h(float f) {
  _Float16 h = (_Float16)f;
  return __builtin_bit_cast(unsigned short, h);
}
__device__ __forceinline__ float h2f(unsigned short u) {
  return (float)__builtin_bit_cast(_Float16, u);
}
__device__ __forceinline__ unsigned int pk2(float a, float b) {
  return __builtin_bit_cast(unsigned int, __builtin_amdgcn_cvt_pkrtz(a, b));
}

// ------------- K1b: weights f32 [256][512] -> f16 transposed [512][256] -----
__global__ __launch_bounds__(256) void k_convert_w(
    const float* __restrict__ Wk, const float* __restrict__ Wv,
    const float* __restrict__ Wq, const float* __restrict__ Wr,
    unsigned short* __restrict__ WT) {
  int o = blockIdx.x * 256 + threadIdx.x;  // 0..524287
  int mat = o >> 17, rem = o & 131071;
  int n = rem >> 8, k = rem & 255;
  const float* W = mat == 0 ? Wk : mat == 1 ? Wv : mat == 2 ? Wq : Wr;
  WT[o] = f2h(W[k * 512 + n]);
}

// ---------------- K2: projection GEMMs, 2-deep prefetch, 1 barrier/iter ----
// 1024 blocks x 512 thr: BM=128, BN=256, BK=32, 8 K-steps. 2 blocks/CU.
// B: quad-buffered GLDS issued 2 tiles ahead (WITH the n0 offset -- R24 bug);
// A: f32->regs 2 tiles ahead -> pk2 -> ds_write (dbuf).
__global__ __launch_bounds__(512) void k_gemm(
    const float* __restrict__ k0, const float* __restrict__ v0,
    const float* __restrict__ q0, const unsigned short* __restrict__ WT,
    const float* __restrict__ bk, const float* __restrict__ bv,
    const float* __restrict__ bq, const float* __restrict__ br,
    unsigned short* __restrict__ Kb, unsigned short* __restrict__ Vh,
    unsigned short* __restrict__ Qb, unsigned short* __restrict__ Rh) {
  const float CS = 0.70710678118654752f * 1.44269504088896341f;
  int b = blockIdx.x;                     // 1024 blocks
  int id2 = (b & 7) * 128 + (b >> 3);     // XCD-bijective
  int mat = id2 >> 8, rest = id2 & 255, my = rest >> 1, nx = rest & 1;
  const float* A = mat == 0 ? k0 : mat == 1 ? v0 : q0;  // mat 3 shares query0
  const unsigned short* Wm = WT + mat * 131072;
  const float* bias = mat == 0 ? bk : mat == 1 ? bv : mat == 2 ? bq : br;
  unsigned short* C = mat == 0 ? Kb : mat == 1 ? Vh : mat == 2 ? Qb : Rh;
  __shared__ __align__(16) unsigned short As[2][4096];  // [128][32] f16
  __shared__ __align__(16) unsigned short Bs[4][8192];  // [256 n][32 k] f16 x4
  int m0 = my * 128, n0 = nx * 256;
  int tid = threadIdx.x, lane = tid & 63, w = tid >> 6;  // 8 waves
  int wm = w >> 2, wn = w & 3, q = lane & 15, hi = lane >> 4;
  f32x4 acc[4][4];
#pragma unroll
  for (int i = 0; i < 4; ++i)
#pragma unroll
    for (int j = 0; j < 4; ++j) acc[i][j] = f32x4{0.f, 0.f, 0.f, 0.f};

  // bias first (oldest in queue; drained by the prologue vmcnt)
  float bsv[4];
#pragma unroll
  for (int j = 0; j < 4; ++j) bsv[j] = bias[n0 + wn * 64 + j * 16 + q];
  MEMFENCE;

  // B chunks: c = i*512 + tid (i=0,1); n = n0 + (c>>2), kq = c&3
  int c0 = tid, c1 = 512 + tid;
  const unsigned short* gB0 = Wm + (n0 + (c0 >> 2)) * 256 + (c0 & 3) * 8;
  const unsigned short* gB1 = Wm + (n0 + (c1 >> 2)) * 256 + (c1 & 3) * 8;
  char* BsB = (char*)&Bs[0][0];
  // A: thread covers row=tid>>2, cols (tid&3)*8..+8 (2x float4)
  const float* gA = A + (m0 + (tid >> 2)) * 256 + (tid & 3) * 8;
  int aoff = (tid >> 2) * 64 + (tid & 3) * 16;  // byte offset in As buf
  float4 aA[2], aB[2];  // slot[parity]: {lo4, hi4}

  // ---- prologue: B0, A0, B1, A1 (order pinned) ----
  GLDS16(gB0, BsB + c0 * 16);
  GLDS16(gB1, BsB + c1 * 16);
  MEMFENCE;
  aA[0] = *(const float4*)gA;
  aB[0] = *(const float4*)(gA + 4);
  MEMFENCE;
  GLDS16(gB0 + 32, BsB + 16384 + c0 * 16);
  GLDS16(gB1 + 32, BsB + 16384 + c1 * 16);
  MEMFENCE;
  aA[1] = *(const float4*)(gA + 32);
  aB[1] = *(const float4*)(gA + 36);
  // queue: [bias*4, B0*2, A0*2, B1*2, A1*2]; vmcnt(4) leaves [B1*2, A1*2]
  asm volatile("s_waitcnt vmcnt(4)" ::: "memory");
  {
    u32x4 wv = {pk2(aA[0].x, aA[0].y), pk2(aA[0].z, aA[0].w),
                pk2(aB[0].x, aB[0].y), pk2(aB[0].z, aB[0].w)};
    *(u32x4*)((char*)&As[0][0] + aoff) = wv;
  }
  asm volatile("s_waitcnt lgkmcnt(0)" ::: "memory");
  __builtin_amdgcn_s_barrier();
  __builtin_amdgcn_sched_barrier(0);

#pragma unroll
  for (int kt = 0; kt < 8; ++kt) {
    int cur = kt & 1, nxt = cur ^ 1;
    // epoch kt issues: tile kt+2 (B -> buf[(kt+2)&3], A -> slot[kt&1])
    if (kt <= 5) {
      GLDS16(gB0 + (kt + 2) * 32, BsB + ((kt + 2) & 3) * 16384 + c0 * 16);
      GLDS16(gB1 + (kt + 2) * 32, BsB + ((kt + 2) & 3) * 16384 + c1 * 16);
      MEMFENCE;
      aA[cur] = *(const float4*)(gA + (kt + 2) * 32);
      aB[cur] = *(const float4*)(gA + (kt + 2) * 32 + 4);
      MEMFENCE;
    }

    f16x8 af[4], bf[4];
#pragma unroll
    for (int i = 0; i < 4; ++i)
      af[i] = *(const f16x8*)((char*)&As[cur][0] +
                              (wm * 64 + i * 16 + q) * 64 + hi * 16);
#pragma unroll
    for (int j = 0; j < 4; ++j)
      bf[j] = *(const f16x8*)(BsB + (kt & 3) * 16384 +
                              (wn * 64 + j * 16 + q) * 64 + hi * 16);
#pragma unroll
    for (int i = 0; i < 4; ++i)
#pragma unroll
      for (int j = 0; j < 4; ++j)
        acc[i][j] = __builtin_amdgcn_mfma_f32_16x16x32_f16(af[i], bf[j], acc[i][j], 0, 0, 0);

    if (kt < 7) {
      // drain tile kt+1 (keeps kt+2's 4 in flight when kt<=5)
      if (kt <= 5) asm volatile("s_waitcnt vmcnt(4)" ::: "memory");
      else asm volatile("s_waitcnt vmcnt(0)" ::: "memory");
      u32x4 wv = {pk2(aA[nxt].x, aA[nxt].y), pk2(aA[nxt].z, aA[nxt].w),
                  pk2(aB[nxt].x, aB[nxt].y), pk2(aB[nxt].z, aB[nxt].w)};
      *(u32x4*)((char*)&As[nxt][0] + aoff) = wv;
    }
    asm volatile("s_waitcnt lgkmcnt(0)" ::: "memory");
    __builtin_amdgcn_s_barrier();
    __builtin_amdgcn_sched_barrier(0);
  }

  float scale = (mat == 2) ? CS : 1.0f;
#pragma unroll
  for (int j = 0; j < 4; ++j) {
    int col = n0 + wn * 64 + j * 16 + q;
    float bs = bsv[j];
#pragma unroll
    for (int i = 0; i < 4; ++i) {
      int rb = m0 + wm * 64 + i * 16 + 4 * hi;
#pragma unroll
      for (int r = 0; r < 4; ++r) {
        float v = (acc[i][j][r] + bs) * scale;
        C[(rb + r) * 512 + col] = f2h(v);
      }
    }
  }
}

// ---------------- K3: attention (32x32 MFMA, T12, fused V-transpose) -------
// (R23-verified, 57.4us; launched <<<256,1024>>>.)
#define QK2(dst, kk0, kk1, qtl)                                               \
  dst = __builtin_amdgcn_mfma_f32_32x32x16_f16(kk0, qf[qtl][0], neg24, 0, 0, 0); \
  dst = __builtin_amdgcn_mfma_f32_32x32x16_f16(kk1, qf[qtl][1], dst, 0, 0, 0);

#define LOADKF(kv, blk, d0, d1)                                               \
  d0 = *(const f16x8*)(Ks + (kbase ^ 0) + (kv) * 4096 + (blk) * 2048);        \
  d1 = *(const f16x8*)(Ks + (kbase ^ 32) + (kv) * 4096 + (blk) * 2048);

#define LOADVF(kv, blk, d0, d1)                                               \
  d0 = *(const f16x8*)(Vs + ((vbase ^ ((2 * (blk)) << 5)) + (kv) * 128));     \
  d1 = *(const f16x8*)(Vs + ((vbase ^ ((2 * (blk) + 1) << 5)) + (kv) * 128));

#define PROC(st, qtl, vv0, vv1)                                               \
  {                                                                           \
    unsigned int w_[8];                                                       \
    _Pragma("unroll") for (int m = 0; m < 8; ++m) {                           \
      float p0_ = __builtin_amdgcn_exp2f(st[2 * m]);                          \
      float p1_ = __builtin_amdgcn_exp2f(st[2 * m + 1]);                      \
      w_[m] = pk2(p0_, p1_);                                                  \
    }                                                                         \
    _Pragma("unroll") for (int m = 0; m < 8; ++m)                             \
      lacc[qtl] = __builtin_amdgcn_fdot2(__builtin_bit_cast(f16x2, w_[m]),    \
                                         ones2, lacc[qtl], false);            \
    unsigned int a0_ = w_[0], a2_ = w_[2], a1_ = w_[1], a3_ = w_[3];          \
    unsigned int b0_ = w_[4], b2_ = w_[6], b1_ = w_[5], b3_ = w_[7];          \
    asm("v_permlane32_swap_b32 %0, %1" : "+v"(a0_), "+v"(a2_));               \
    asm("v_permlane32_swap_b32 %0, %1" : "+v"(a1_), "+v"(a3_));               \
    asm("v_permlane32_swap_b32 %0, %1" : "+v"(b0_), "+v"(b2_));               \
    asm("v_permlane32_swap_b32 %0, %1" : "+v"(b1_), "+v"(b3_));               \
    f16x8 pb0_ = __builtin_bit_cast(f16x8, (u32x4){a0_, a1_, a2_, a3_});      \
    f16x8 pb1_ = __builtin_bit_cast(f16x8, (u32x4){b0_, b1_, b2_, b3_});      \
    o[qtl] = __builtin_amdgcn_mfma_f32_32x32x16_f16(vv0, pb0_, o[qtl], 0, 0, 0); \
    o[qtl] = __builtin_amdgcn_mfma_f32_32x32x16_f16(vv1, pb1_, o[qtl], 0, 0, 0); \
  }

__global__ __launch_bounds__(1024) void k_attn(
    const unsigned short* __restrict__ Kb, const unsigned short* __restrict__ Vh,
    const unsigned short* __restrict__ Qb, const unsigned short* __restrict__ Rh,
    float* __restrict__ out) {
  __shared__ __align__(16) char Ks[65536];  // [1024 s][32 d] swizzled
  __shared__ __align__(16) char Vs[65536];  // [32 d][1024 s] swizzled

  int p = blockIdx.x;                 // 256 blocks, 1 per group
  int g = (p & 7) * 32 + (p >> 3);    // XCD-bijective
  int tid = threadIdx.x, lane = tid & 63, wid = tid >> 6;
  int q = lane & 31, h2 = lane >> 5;

  const char* Ksrc = (const char*)Kb + (size_t)g * 65536;
#pragma unroll
  for (int r = 0; r < 4; ++r) {
    int dk = tid * 16 + r * 16384;
    GLDS16(Ksrc + (dk ^ (((dk >> 7) & 7) << 4)), Ks + dk);
  }

  // V: k_vt-shape transpose from Vh[s][d] into swizzled Vs[d][s]
  {
    const unsigned short* VhG = Vh + g * 32768;
    int d = tid & 31, s8b = tid >> 5;
#pragma unroll
    for (int it = 0; it < 4; ++it) {
      int s8 = s8b + it * 32;
      us8 v;
#pragma unroll
      for (int i = 0; i < 8; ++i) v[i] = VhG[(s8 * 8 + i) * 32 + d];
      *(us8*)(Vs + ((d * 2048 + s8 * 16) ^ ((d & 7) << 4))) = v;
    }
  }

  const unsigned short* Qg = Qb + g * 32768 + wid * 2048;
  f16x8 qf[2][2];
#pragma unroll
  for (int qt = 0; qt < 2; ++qt)
#pragma unroll
    for (int kh = 0; kh < 2; ++kh)
      qf[qt][kh] = *(const f16x8*)&Qg[(qt * 32 + q) * 32 + kh * 16 + h2 * 8];

  int kbase = (q * 64 + h2 * 16) ^ (((q >> 1) & 7) << 4);
  int vbase = (q * 2048 + h2 * 16) ^ ((q & 7) << 4);

  const f16x2 ones2 = {(_Float16)1.0f, (_Float16)1.0f};
  f32x16 o[2];
#pragma unroll
  for (int i = 0; i < 16; ++i) { o[0][i] = 0.f; o[1][i] = 0.f; }
  float lacc[2] = {0.f, 0.f};
  f32x16 neg24;
#pragma unroll
  for (int i = 0; i < 16; ++i) neg24[i] = -24.f;

  __syncthreads();  // drains GLDS (vmcnt) + ds_writes (lgkm) for all waves

  f16x8 k0A, k1A, v0A, v1A, k0B, k1B, v0B, v1B;
  f32x16 stA, s1, s2, s3;
  LOADKF(0, 0, k0A, k1A);
  LOADVF(0, 0, v0A, v1A);
  QK2(stA, k0A, k1A, 0);

  for (int kv = 0; kv < 16; ++kv) {
    QK2(s1, k0A, k1A, 1);
    PROC(stA, 0, v0A, v1A);
    LOADKF(kv, 1, k0B, k1B);
    LOADVF(kv, 1, v0B, v1B);
    QK2(s2, k0B, k1B, 0);
    PROC(s1, 1, v0A, v1A);
    QK2(s3, k0B, k1B, 1);
    PROC(s2, 0, v0B, v1B);
    if (kv < 15) {
      LOADKF(kv + 1, 0, k0A, k1A);
      LOADVF(kv + 1, 0, v0A, v1A);
      QK2(stA, k0A, k1A, 0);
    }
    PROC(s3, 1, v0B, v1B);
  }

#pragma unroll
  for (int qt = 0; qt < 2; ++qt)
    lacc[qt] += __shfl_xor(lacc[qt], 32, 64);

#pragma unroll
  for (int qt = 0; qt < 2; ++qt) {
    float iv = 1.0f / lacc[qt];
    int rowoff = g * 32768 + (wid * 64 + qt * 32 + q) * 32;
#pragma unroll
    for (int rg = 0; rg < 4; ++rg) {
      int off = rowoff + rg * 8 + h2 * 4;   // d = (r&3) + 8*rg + 4*h2
      ushort4 rr = *(const ushort4*)&Rh[off];
      float4 ov;
      ov.x = fmaxf(h2f(rr.x) + o[qt][4 * rg + 0] * iv, 0.f);
      ov.y = fmaxf(h2f(rr.y) + o[qt][4 * rg + 1] * iv, 0.f);
      ov.z = fmaxf(h2f(rr.z) + o[qt][4 * rg + 2] * iv, 0.f);
      ov.w = fmaxf(h2f(rr.w) + o[qt][4 * rg + 3] * iv, 0.f);
      *(float4*)&out[off] = ov;
    }
  }
}

extern "C" void kernel_launch(void* const* d_in, const int* in_sizes, int n_in,
                              void* d_out, int out_size, void* d_ws, size_t ws_size,
                              hipStream_t stream) {
  const float* key0 = (const float*)d_in[0];
  const float* value0 = (const float*)d_in[1];
  const float* query0 = (const float*)d_in[2];
  const float* Wk = (const float*)d_in[3];
  const float* bk = (const float*)d_in[4];
  const float* Wv = (const float*)d_in[5];
  const float* bv = (const float*)d_in[6];
  const float* Wq = (const float*)d_in[7];
  const float* bq = (const float*)d_in[8];
  const float* Wr = (const float*)d_in[9];
  const float* br = (const float*)d_in[10];
  float* out = (float*)d_out;
  char* ws = (char*)d_ws;
  unsigned short* Kb = (unsigned short*)(ws);              // 16 MB f16 [16384,512]
  unsigned short* Vh = (unsigned short*)(ws + 16777216);   // 16 MB f16 [16384,512]
  unsigned short* Qb = (unsigned short*)(ws + 33554432);   // 16 MB f16 (pre-scaled)
  unsigned short* Rh = (unsigned short*)(ws + 50331648);   // 16 MB f16 [16384,512]
  unsigned short* WT = (unsigned short*)(ws + 92274688);   // 1 MB f16 [4][512][256]

  k_convert_w<<<dim3(2048), dim3(256), 0, stream>>>(Wk, Wv, Wq, Wr, WT);
  k_gemm<<<dim3(1024), dim3(512), 0, stream>>>(key0, value0, query0, WT,
                                               bk, bv, bq, br, Kb, Vh, Qb, Rh);
  k_attn<<<dim3(256), dim3(1024), 0, stream>>>(Kb, Vh, Qb, Rh, out);
}

// Round 26
// 96.589 us; speedup vs baseline: 1.0316x; 1.0316x over previous
//
#include <hip/hip_runtime.h>
#include <hip/hip_bf16.h>

typedef _Float16 f16x8 __attribute__((ext_vector_type(8)));
typedef _Float16 f16x2 __attribute__((ext_vector_type(2)));
typedef float f32x4 __attribute__((ext_vector_type(4)));
typedef float f32x16 __attribute__((ext_vector_type(16)));
typedef unsigned int u32x2 __attribute__((ext_vector_type(2)));
typedef unsigned int u32x4 __attribute__((ext_vector_type(4)));
typedef unsigned short us8 __attribute__((ext_vector_type(8)));

#define GLDS16(gp, lp)                                                        \
  __builtin_amdgcn_global_load_lds(                                           \
      (const __attribute__((address_space(1))) void*)(gp),                    \
      (__attribute__((address_space(3))) void*)(lp), 16, 0, 0)

__device__ __forceinline__ unsigned short f2h(float f) {
  _Float16 h = (_Float16)f;
  return __builtin_bit_cast(unsigned short, h);
}
__device__ __forceinline__ float h2f(unsigned short u) {
  return (float)__builtin_bit_cast(_Float16, u);
}
__device__ __forceinline__ unsigned int pk2(float a, float b) {
  return __builtin_bit_cast(unsigned int, __builtin_amdgcn_cvt_pkrtz(a, b));
}

// ------------- K1b: weights f32 [256][512] -> f16 transposed [512][256] -----
__global__ __launch_bounds__(256) void k_convert_w(
    const float* __restrict__ Wk, const float* __restrict__ Wv,
    const float* __restrict__ Wq, const float* __restrict__ Wr,
    unsigned short* __restrict__ WT) {
  int o = blockIdx.x * 256 + threadIdx.x;  // 0..524287
  int mat = o >> 17, rem = o & 131071;
  int n = rem >> 8, k = rem & 255;
  const float* W = mat == 0 ? Wk : mat == 1 ? Wv : mat == 2 ? Wq : Wr;
  WT[o] = f2h(W[k * 512 + n]);
}

// ---------------- K2: 4 projection GEMMs, counted-vmcnt (R18/R23-verified) -
// BM=128, BN=512, BK=32; issue-before-wait, 2 barriers/step, counted vmcnt.
__global__ __launch_bounds__(1024) void k_gemm(
    const float* __restrict__ k0, const float* __restrict__ v0,
    const float* __restrict__ q0, const unsigned short* __restrict__ WT,
    const float* __restrict__ bk, const float* __restrict__ bv,
    const float* __restrict__ bq, const float* __restrict__ br,
    unsigned short* __restrict__ Kb, unsigned short* __restrict__ Vh,
    unsigned short* __restrict__ Qb, unsigned short* __restrict__ Rh) {
  const float CS = 0.70710678118654752f * 1.44269504088896341f;
  int b = blockIdx.x;                 // 512 blocks
  int mat = b >> 7, my = b & 127;
  const float* A = mat == 0 ? k0 : mat == 1 ? v0 : q0;  // mat 3 shares query0
  const unsigned short* Wm = WT + mat * 131072;
  const float* bias = mat == 0 ? bk : mat == 1 ? bv : mat == 2 ? bq : br;
  unsigned short* C = mat == 0 ? Kb : mat == 1 ? Vh : mat == 2 ? Qb : Rh;
  __shared__ __align__(16) unsigned short As[2][4096];   // [128][32] f16
  __shared__ __align__(16) unsigned short Bs[2][16384];  // [512 n][32 k] f16
  int m0 = my * 128;
  int tid = threadIdx.x, lane = tid & 63, w = tid >> 6;
  int wm = w >> 3, wn = w & 7, q = lane & 15, hi = lane >> 4;
  f32x4 acc[4][4];
#pragma unroll
  for (int i = 0; i < 4; ++i)
#pragma unroll
    for (int j = 0; j < 4; ++j) acc[i][j] = f32x4{0.f, 0.f, 0.f, 0.f};

  float bsv[4];
#pragma unroll
  for (int j = 0; j < 4; ++j) bsv[j] = bias[wn * 64 + j * 16 + q];

  const float* gA = A + (m0 + (tid >> 3)) * 256 + (tid & 7) * 4;
  const unsigned short* gB = Wm + (tid >> 2) * 256 + (tid & 3) * 8;

  float4 arF[2];
  arF[0] = *(const float4*)gA;
  arF[1] = *(const float4*)(gA + 32);
  GLDS16(gB, &Bs[0][tid * 8]);
  GLDS16(gB + 65536, &Bs[0][8192 + tid * 8]);
  asm volatile("s_waitcnt vmcnt(3)" ::: "memory");
  *(u32x2*)&As[0][tid * 4] =
      u32x2{pk2(arF[0].x, arF[0].y), pk2(arF[0].z, arF[0].w)};
  asm volatile("s_waitcnt lgkmcnt(0)" ::: "memory");
  __builtin_amdgcn_s_barrier();
  __builtin_amdgcn_sched_barrier(0);

#pragma unroll
  for (int kt = 0; kt < 8; ++kt) {
    int cur = kt & 1, nxt = cur ^ 1;
    if (kt < 6) arF[cur] = *(const float4*)(gA + (kt + 2) * 32);
    if (kt < 7) {
      GLDS16(gB + (kt + 1) * 32, &Bs[nxt][tid * 8]);
      GLDS16(gB + (kt + 1) * 32 + 65536, &Bs[nxt][8192 + tid * 8]);
    }
    if (kt < 6) asm volatile("s_waitcnt vmcnt(3)" ::: "memory");
    else if (kt == 6) asm volatile("s_waitcnt vmcnt(2)" ::: "memory");
    else asm volatile("s_waitcnt vmcnt(0)" ::: "memory");
    __builtin_amdgcn_s_barrier();
    __builtin_amdgcn_sched_barrier(0);

    f16x8 af[4], bf[4];
#pragma unroll
    for (int i = 0; i < 4; ++i)
      af[i] = *(const f16x8*)&As[cur][(wm * 64 + i * 16 + q) * 32 + hi * 8];
#pragma unroll
    for (int j = 0; j < 4; ++j)
      bf[j] = *(const f16x8*)&Bs[cur][(wn * 64 + j * 16 + q) * 32 + hi * 8];
#pragma unroll
    for (int i = 0; i < 4; ++i)
#pragma unroll
      for (int j = 0; j < 4; ++j)
        acc[i][j] = __builtin_amdgcn_mfma_f32_16x16x32_f16(af[i], bf[j], acc[i][j], 0, 0, 0);

    if (kt < 7) {
      *(u32x2*)&As[nxt][tid * 4] =
          u32x2{pk2(arF[nxt].x, arF[nxt].y), pk2(arF[nxt].z, arF[nxt].w)};
    }
    asm volatile("s_waitcnt lgkmcnt(0)" ::: "memory");
    __builtin_amdgcn_s_barrier();
    __builtin_amdgcn_sched_barrier(0);
  }

  float scale = (mat == 2) ? CS : 1.0f;
#pragma unroll
  for (int j = 0; j < 4; ++j) {
    int col = wn * 64 + j * 16 + q;
    float bs = bsv[j];
#pragma unroll
    for (int i = 0; i < 4; ++i) {
      int rb = m0 + wm * 64 + i * 16 + 4 * hi;
#pragma unroll
      for (int r = 0; r < 4; ++r) {
        float v = (acc[i][j][r] + bs) * scale;
        C[(rb + r) * 512 + col] = f2h(v);
      }
    }
  }
}

// ---------------- K3: attention (32x32 MFMA, T12, fused V-transpose) -------
// (R23-verified, 57.4us; launched <<<256,1024>>>.)
#define QK2(dst, kk0, kk1, qtl)                                               \
  dst = __builtin_amdgcn_mfma_f32_32x32x16_f16(kk0, qf[qtl][0], neg24, 0, 0, 0); \
  dst = __builtin_amdgcn_mfma_f32_32x32x16_f16(kk1, qf[qtl][1], dst, 0, 0, 0);

#define LOADKF(kv, blk, d0, d1)                                               \
  d0 = *(const f16x8*)(Ks + (kbase ^ 0) + (kv) * 4096 + (blk) * 2048);        \
  d1 = *(const f16x8*)(Ks + (kbase ^ 32) + (kv) * 4096 + (blk) * 2048);

#define LOADVF(kv, blk, d0, d1)                                               \
  d0 = *(const f16x8*)(Vs + ((vbase ^ ((2 * (blk)) << 5)) + (kv) * 128));     \
  d1 = *(const f16x8*)(Vs + ((vbase ^ ((2 * (blk) + 1) << 5)) + (kv) * 128));

#define PROC(st, qtl, vv0, vv1)                                               \
  {                                                                           \
    unsigned int w_[8];                                                       \
    _Pragma("unroll") for (int m = 0; m < 8; ++m) {                           \
      float p0_ = __builtin_amdgcn_exp2f(st[2 * m]);                          \
      float p1_ = __builtin_amdgcn_exp2f(st[2 * m + 1]);                      \
      w_[m] = pk2(p0_, p1_);                                                  \
    }                                                                         \
    _Pragma("unroll") for (int m = 0; m < 8; ++m)                             \
      lacc[qtl] = __builtin_amdgcn_fdot2(__builtin_bit_cast(f16x2, w_[m]),    \
                                         ones2, lacc[qtl], false);            \
    unsigned int a0_ = w_[0], a2_ = w_[2], a1_ = w_[1], a3_ = w_[3];          \
    unsigned int b0_ = w_[4], b2_ = w_[6], b1_ = w_[5], b3_ = w_[7];          \
    asm("v_permlane32_swap_b32 %0, %1" : "+v"(a0_), "+v"(a2_));               \
    asm("v_permlane32_swap_b32 %0, %1" : "+v"(a1_), "+v"(a3_));               \
    asm("v_permlane32_swap_b32 %0, %1" : "+v"(b0_), "+v"(b2_));               \
    asm("v_permlane32_swap_b32 %0, %1" : "+v"(b1_), "+v"(b3_));               \
    f16x8 pb0_ = __builtin_bit_cast(f16x8, (u32x4){a0_, a1_, a2_, a3_});      \
    f16x8 pb1_ = __builtin_bit_cast(f16x8, (u32x4){b0_, b1_, b2_, b3_});      \
    o[qtl] = __builtin_amdgcn_mfma_f32_32x32x16_f16(vv0, pb0_, o[qtl], 0, 0, 0); \
    o[qtl] = __builtin_amdgcn_mfma_f32_32x32x16_f16(vv1, pb1_, o[qtl], 0, 0, 0); \
  }

__global__ __launch_bounds__(1024) void k_attn(
    const unsigned short* __restrict__ Kb, const unsigned short* __restrict__ Vh,
    const unsigned short* __restrict__ Qb, const unsigned short* __restrict__ Rh,
    float* __restrict__ out) {
  __shared__ __align__(16) char Ks[65536];  // [1024 s][32 d] swizzled
  __shared__ __align__(16) char Vs[65536];  // [32 d][1024 s] swizzled

  int p = blockIdx.x;                 // 256 blocks, 1 per group
  int g = (p & 7) * 32 + (p >> 3);    // XCD-bijective
  int tid = threadIdx.x, lane = tid & 63, wid = tid >> 6;
  int q = lane & 31, h2 = lane >> 5;

  const char* Ksrc = (const char*)Kb + (size_t)g * 65536;
#pragma unroll
  for (int r = 0; r < 4; ++r) {
    int dk = tid * 16 + r * 16384;
    GLDS16(Ksrc + (dk ^ (((dk >> 7) & 7) << 4)), Ks + dk);
  }

  // V: k_vt-shape transpose from Vh[s][d] into swizzled Vs[d][s]
  {
    const unsigned short* VhG = Vh + g * 32768;
    int d = tid & 31, s8b = tid >> 5;
#pragma unroll
    for (int it = 0; it < 4; ++it) {
      int s8 = s8b + it * 32;
      us8 v;
#pragma unroll
      for (int i = 0; i < 8; ++i) v[i] = VhG[(s8 * 8 + i) * 32 + d];
      *(us8*)(Vs + ((d * 2048 + s8 * 16) ^ ((d & 7) << 4))) = v;
    }
  }

  const unsigned short* Qg = Qb + g * 32768 + wid * 2048;
  f16x8 qf[2][2];
#pragma unroll
  for (int qt = 0; qt < 2; ++qt)
#pragma unroll
    for (int kh = 0; kh < 2; ++kh)
      qf[qt][kh] = *(const f16x8*)&Qg[(qt * 32 + q) * 32 + kh * 16 + h2 * 8];

  int kbase = (q * 64 + h2 * 16) ^ (((q >> 1) & 7) << 4);
  int vbase = (q * 2048 + h2 * 16) ^ ((q & 7) << 4);

  const f16x2 ones2 = {(_Float16)1.0f, (_Float16)1.0f};
  f32x16 o[2];
#pragma unroll
  for (int i = 0; i < 16; ++i) { o[0][i] = 0.f; o[1][i] = 0.f; }
  float lacc[2] = {0.f, 0.f};
  f32x16 neg24;
#pragma unroll
  for (int i = 0; i < 16; ++i) neg24[i] = -24.f;

  __syncthreads();  // drains GLDS (vmcnt) + ds_writes (lgkm) for all waves

  f16x8 k0A, k1A, v0A, v1A, k0B, k1B, v0B, v1B;
  f32x16 stA, s1, s2, s3;
  LOADKF(0, 0, k0A, k1A);
  LOADVF(0, 0, v0A, v1A);
  QK2(stA, k0A, k1A, 0);

  for (int kv = 0; kv < 16; ++kv) {
    QK2(s1, k0A, k1A, 1);
    PROC(stA, 0, v0A, v1A);
    LOADKF(kv, 1, k0B, k1B);
    LOADVF(kv, 1, v0B, v1B);
    QK2(s2, k0B, k1B, 0);
    PROC(s1, 1, v0A, v1A);
    QK2(s3, k0B, k1B, 1);
    PROC(s2, 0, v0B, v1B);
    if (kv < 15) {
      LOADKF(kv + 1, 0, k0A, k1A);
      LOADVF(kv + 1, 0, v0A, v1A);
      QK2(stA, k0A, k1A, 0);
    }
    PROC(s3, 1, v0B, v1B);
  }

#pragma unroll
  for (int qt = 0; qt < 2; ++qt)
    lacc[qt] += __shfl_xor(lacc[qt], 32, 64);

#pragma unroll
  for (int qt = 0; qt < 2; ++qt) {
    float iv = 1.0f / lacc[qt];
    int rowoff = g * 32768 + (wid * 64 + qt * 32 + q) * 32;
#pragma unroll
    for (int rg = 0; rg < 4; ++rg) {
      int off = rowoff + rg * 8 + h2 * 4;   // d = (r&3) + 8*rg + 4*h2
      ushort4 rr = *(const ushort4*)&Rh[off];
      float4 ov;
      ov.x = fmaxf(h2f(rr.x) + o[qt][4 * rg + 0] * iv, 0.f);
      ov.y = fmaxf(h2f(rr.y) + o[qt][4 * rg + 1] * iv, 0.f);
      ov.z = fmaxf(h2f(rr.z) + o[qt][4 * rg + 2] * iv, 0.f);
      ov.w = fmaxf(h2f(rr.w) + o[qt][4 * rg + 3] * iv, 0.f);
      *(float4*)&out[off] = ov;
    }
  }
}

extern "C" void kernel_launch(void* const* d_in, const int* in_sizes, int n_in,
                              void* d_out, int out_size, void* d_ws, size_t ws_size,
                              hipStream_t stream) {
  const float* key0 = (const float*)d_in[0];
  const float* value0 = (const float*)d_in[1];
  const float* query0 = (const float*)d_in[2];
  const float* Wk = (const float*)d_in[3];
  const float* bk = (const float*)d_in[4];
  const float* Wv = (const float*)d_in[5];
  const float* bv = (const float*)d_in[6];
  const float* Wq = (const float*)d_in[7];
  const float* bq = (const float*)d_in[8];
  const float* Wr = (const float*)d_in[9];
  const float* br = (const float*)d_in[10];
  float* out = (float*)d_out;
  char* ws = (char*)d_ws;
  unsigned short* Kb = (unsigned short*)(ws);              // 16 MB f16 [16384,512]
  unsigned short* Vh = (unsigned short*)(ws + 16777216);   // 16 MB f16 [16384,512]
  unsigned short* Qb = (unsigned short*)(ws + 33554432);   // 16 MB f16 (pre-scaled)
  unsigned short* Rh = (unsigned short*)(ws + 50331648);   // 16 MB f16 [16384,512]
  unsigned short* WT = (unsigned short*)(ws + 92274688);   // 1 MB f16 [4][512][256]

  k_convert_w<<<dim3(2048), dim3(256), 0, stream>>>(Wk, Wv, Wq, Wr, WT);
  k_gemm<<<dim3(512), dim3(1024), 0, stream>>>(key0, value0, query0, WT,
                                               bk, bv, bq, br, Kb, Vh, Qb, Rh);
  k_attn<<<dim3(256), dim3(1024), 0, stream>>>(Kb, Vh, Qb, Rh, out);
}

// Round 27
// 95.125 us; speedup vs baseline: 1.0475x; 1.0154x over previous
//
#include <hip/hip_runtime.h>
#include <hip/hip_bf16.h>

typedef _Float16 f16x8 __attribute__((ext_vector_type(8)));
typedef _Float16 f16x2 __attribute__((ext_vector_type(2)));
typedef float f32x4 __attribute__((ext_vector_type(4)));
typedef float f32x16 __attribute__((ext_vector_type(16)));
typedef unsigned int u32x2 __attribute__((ext_vector_type(2)));
typedef unsigned int u32x4 __attribute__((ext_vector_type(4)));
typedef unsigned short us8 __attribute__((ext_vector_type(8)));

#define GLDS16(gp, lp)                                                        \
  __builtin_amdgcn_global_load_lds(                                           \
      (const __attribute__((address_space(1))) void*)(gp),                    \
      (__attribute__((address_space(3))) void*)(lp), 16, 0, 0)

#define MEMFENCE asm volatile("" ::: "memory")

__device__ __forceinline__ unsigned short f2h(float f) {
  _Float16 h = (_Float16)f;
  return __builtin_bit_cast(unsigned short, h);
}
__device__ __forceinline__ float h2f(unsigned short u) {
  return (float)__builtin_bit_cast(_Float16, u);
}
__device__ __forceinline__ unsigned int pk2(float a, float b) {
  return __builtin_bit_cast(unsigned int, __builtin_amdgcn_cvt_pkrtz(a, b));
}

// ------------- K1b: weights f32 [256][512] -> f16 transposed [512][256] -----
__global__ __launch_bounds__(256) void k_convert_w(
    const float* __restrict__ Wk, const float* __restrict__ Wv,
    const float* __restrict__ Wq, const float* __restrict__ Wr,
    unsigned short* __restrict__ WT) {
  int o = blockIdx.x * 256 + threadIdx.x;  // 0..524287
  int mat = o >> 17, rem = o & 131071;
  int n = rem >> 8, k = rem & 255;
  const float* W = mat == 0 ? Wk : mat == 1 ? Wv : mat == 2 ? Wq : Wr;
  WT[o] = f2h(W[k * 512 + n]);
}

// ---------------- K2: projection GEMMs, R18 ledger @ 512thr/BN=256 ---------
// 1024 blocks x 512 thr: BM=128, BN=256, BK=32, 8 K-steps; LDS 48KB ->
// 2 blocks/CU = 2 independent barrier domains (the R18 1-block layout
// stalled all 16 waves at every barrier). Issue-before-wait, counted vmcnt:
// prologue vmcnt(4); loop 4/4/4/4/4/4/2/0.
__global__ __launch_bounds__(512) void k_gemm(
    const float* __restrict__ k0, const float* __restrict__ v0,
    const float* __restrict__ q0, const unsigned short* __restrict__ WT,
    const float* __restrict__ bk, const float* __restrict__ bv,
    const float* __restrict__ bq, const float* __restrict__ br,
    unsigned short* __restrict__ Kb, unsigned short* __restrict__ Vh,
    unsigned short* __restrict__ Qb, unsigned short* __restrict__ Rh) {
  const float CS = 0.70710678118654752f * 1.44269504088896341f;
  int b = blockIdx.x;                     // 1024 blocks
  int id2 = (b & 7) * 128 + (b >> 3);     // XCD-bijective
  int mat = id2 >> 8, rest = id2 & 255, my = rest >> 1, nx = rest & 1;
  const float* A = mat == 0 ? k0 : mat == 1 ? v0 : q0;  // mat 3 shares query0
  const unsigned short* Wm = WT + mat * 131072;
  const float* bias = mat == 0 ? bk : mat == 1 ? bv : mat == 2 ? bq : br;
  unsigned short* C = mat == 0 ? Kb : mat == 1 ? Vh : mat == 2 ? Qb : Rh;
  __shared__ __align__(16) unsigned short As[2][4096];  // [128][32] f16
  __shared__ __align__(16) unsigned short Bs[2][8192];  // [256 n][32 k] f16
  int m0 = my * 128, n0 = nx * 256;
  int tid = threadIdx.x, lane = tid & 63, w = tid >> 6;  // 8 waves
  int wm = w >> 2, wn = w & 3, q = lane & 15, hi = lane >> 4;
  f32x4 acc[4][4];
#pragma unroll
  for (int i = 0; i < 4; ++i)
#pragma unroll
    for (int j = 0; j < 4; ++j) acc[i][j] = f32x4{0.f, 0.f, 0.f, 0.f};

  // bias first (oldest in vmcnt queue; drained by prologue vmcnt(4))
  float bsv[4];
#pragma unroll
  for (int j = 0; j < 4; ++j) bsv[j] = bias[n0 + wn * 64 + j * 16 + q];
  MEMFENCE;

  // A: thread covers row=tid>>2, cols (tid&3)*8..+8 (2x float4 f32)
  const float* gA = A + (m0 + (tid >> 2)) * 256 + (tid & 3) * 8;
  int aoff = (tid >> 2) * 64 + (tid & 3) * 16;  // byte offset in As buf
  // B chunks: c = i*512 + tid (i=0,1); n = n0 + (c>>2), kq = c&3
  int c0 = tid, c1 = 512 + tid;
  const unsigned short* gB0 = Wm + (n0 + (c0 >> 2)) * 256 + (c0 & 3) * 8;
  const unsigned short* gB1 = Wm + (n0 + (c1 >> 2)) * 256 + (c1 & 3) * 8;

  // ---- prologue: A0, A1 -> regs; B0 -> LDS[0] ----
  float4 aL[2], aH[2];  // slot[parity]: low/high float4
  aL[0] = *(const float4*)gA;
  aH[0] = *(const float4*)(gA + 4);
  aL[1] = *(const float4*)(gA + 32);
  aH[1] = *(const float4*)(gA + 36);
  MEMFENCE;
  GLDS16(gB0, (char*)&Bs[0][0] + c0 * 16);
  GLDS16(gB1, (char*)&Bs[0][0] + c1 * 16);
  // queue: [bias*4, A0*2, A1*2, B0*2]; vmcnt(4) leaves [A1*2, B0*2]
  asm volatile("s_waitcnt vmcnt(4)" ::: "memory");
  {
    u32x4 wv = {pk2(aL[0].x, aL[0].y), pk2(aL[0].z, aL[0].w),
                pk2(aH[0].x, aH[0].y), pk2(aH[0].z, aH[0].w)};
    *(u32x4*)((char*)&As[0][0] + aoff) = wv;
  }
  asm volatile("s_waitcnt lgkmcnt(0)" ::: "memory");
  __builtin_amdgcn_s_barrier();
  __builtin_amdgcn_sched_barrier(0);

#pragma unroll
  for (int kt = 0; kt < 8; ++kt) {
    int cur = kt & 1, nxt = cur ^ 1;
    if (kt < 6) {  // A(kt+2) -> slot[cur]
      aL[cur] = *(const float4*)(gA + (kt + 2) * 32);
      aH[cur] = *(const float4*)(gA + (kt + 2) * 32 + 4);
    }
    MEMFENCE;
    if (kt < 7) {  // B(kt+1) -> Bs[nxt]
      GLDS16(gB0 + (kt + 1) * 32, (char*)&Bs[nxt][0] + c0 * 16);
      GLDS16(gB1 + (kt + 1) * 32, (char*)&Bs[nxt][0] + c1 * 16);
    }
    // drain B(kt)+A(kt+1); keep this iter's 4 issues in flight
    if (kt < 6) asm volatile("s_waitcnt vmcnt(4)" ::: "memory");
    else if (kt == 6) asm volatile("s_waitcnt vmcnt(2)" ::: "memory");
    else asm volatile("s_waitcnt vmcnt(0)" ::: "memory");
    __builtin_amdgcn_s_barrier();
    __builtin_amdgcn_sched_barrier(0);

    f16x8 af[4], bf[4];
#pragma unroll
    for (int i = 0; i < 4; ++i)
      af[i] = *(const f16x8*)((char*)&As[cur][0] +
                              (wm * 64 + i * 16 + q) * 64 + hi * 16);
#pragma unroll
    for (int j = 0; j < 4; ++j)
      bf[j] = *(const f16x8*)((char*)&Bs[cur][0] +
                              (wn * 64 + j * 16 + q) * 64 + hi * 16);
#pragma unroll
    for (int i = 0; i < 4; ++i)
#pragma unroll
      for (int j = 0; j < 4; ++j)
        acc[i][j] = __builtin_amdgcn_mfma_f32_16x16x32_f16(af[i], bf[j], acc[i][j], 0, 0, 0);

    if (kt < 7) {  // park A(kt+1) (slot[nxt], drained by this iter's wait)
      u32x4 wv = {pk2(aL[nxt].x, aL[nxt].y), pk2(aL[nxt].z, aL[nxt].w),
                  pk2(aH[nxt].x, aH[nxt].y), pk2(aH[nxt].z, aH[nxt].w)};
      *(u32x4*)((char*)&As[nxt][0] + aoff) = wv;
    }
    asm volatile("s_waitcnt lgkmcnt(0)" ::: "memory");
    __builtin_amdgcn_s_barrier();
    __builtin_amdgcn_sched_barrier(0);
  }

  float scale = (mat == 2) ? CS : 1.0f;
#pragma unroll
  for (int j = 0; j < 4; ++j) {
    int col = n0 + wn * 64 + j * 16 + q;
    float bs = bsv[j];
#pragma unroll
    for (int i = 0; i < 4; ++i) {
      int rb = m0 + wm * 64 + i * 16 + 4 * hi;
#pragma unroll
      for (int r = 0; r < 4; ++r) {
        float v = (acc[i][j][r] + bs) * scale;
        C[(rb + r) * 512 + col] = f2h(v);
      }
    }
  }
}

// ---------------- K3: attention (32x32 MFMA, T12, fused V-transpose) -------
// (R23/R26-verified, 57.4us; launched <<<256,1024>>>.)
#define QK2(dst, kk0, kk1, qtl)                                               \
  dst = __builtin_amdgcn_mfma_f32_32x32x16_f16(kk0, qf[qtl][0], neg24, 0, 0, 0); \
  dst = __builtin_amdgcn_mfma_f32_32x32x16_f16(kk1, qf[qtl][1], dst, 0, 0, 0);

#define LOADKF(kv, blk, d0, d1)                                               \
  d0 = *(const f16x8*)(Ks + (kbase ^ 0) + (kv) * 4096 + (blk) * 2048);        \
  d1 = *(const f16x8*)(Ks + (kbase ^ 32) + (kv) * 4096 + (blk) * 2048);

#define LOADVF(kv, blk, d0, d1)                                               \
  d0 = *(const f16x8*)(Vs + ((vbase ^ ((2 * (blk)) << 5)) + (kv) * 128));     \
  d1 = *(const f16x8*)(Vs + ((vbase ^ ((2 * (blk) + 1) << 5)) + (kv) * 128));

#define PROC(st, qtl, vv0, vv1)                                               \
  {                                                                           \
    unsigned int w_[8];                                                       \
    _Pragma("unroll") for (int m = 0; m < 8; ++m) {                           \
      float p0_ = __builtin_amdgcn_exp2f(st[2 * m]);                          \
      float p1_ = __builtin_amdgcn_exp2f(st[2 * m + 1]);                      \
      w_[m] = pk2(p0_, p1_);                                                  \
    }                                                                         \
    _Pragma("unroll") for (int m = 0; m < 8; ++m)                             \
      lacc[qtl] = __builtin_amdgcn_fdot2(__builtin_bit_cast(f16x2, w_[m]),    \
                                         ones2, lacc[qtl], false);            \
    unsigned int a0_ = w_[0], a2_ = w_[2], a1_ = w_[1], a3_ = w_[3];          \
    unsigned int b0_ = w_[4], b2_ = w_[6], b1_ = w_[5], b3_ = w_[7];          \
    asm("v_permlane32_swap_b32 %0, %1" : "+v"(a0_), "+v"(a2_));               \
    asm("v_permlane32_swap_b32 %0, %1" : "+v"(a1_), "+v"(a3_));               \
    asm("v_permlane32_swap_b32 %0, %1" : "+v"(b0_), "+v"(b2_));               \
    asm("v_permlane32_swap_b32 %0, %1" : "+v"(b1_), "+v"(b3_));               \
    f16x8 pb0_ = __builtin_bit_cast(f16x8, (u32x4){a0_, a1_, a2_, a3_});      \
    f16x8 pb1_ = __builtin_bit_cast(f16x8, (u32x4){b0_, b1_, b2_, b3_});      \
    o[qtl] = __builtin_amdgcn_mfma_f32_32x32x16_f16(vv0, pb0_, o[qtl], 0, 0, 0); \
    o[qtl] = __builtin_amdgcn_mfma_f32_32x32x16_f16(vv1, pb1_, o[qtl], 0, 0, 0); \
  }

__global__ __launch_bounds__(1024) void k_attn(
    const unsigned short* __restrict__ Kb, const unsigned short* __restrict__ Vh,
    const unsigned short* __restrict__ Qb, const unsigned short* __restrict__ Rh,
    float* __restrict__ out) {
  __shared__ __align__(16) char Ks[65536];  // [1024 s][32 d] swizzled
  __shared__ __align__(16) char Vs[65536];  // [32 d][1024 s] swizzled

  int p = blockIdx.x;                 // 256 blocks, 1 per group
  int g = (p & 7) * 32 + (p >> 3);    // XCD-bijective
  int tid = threadIdx.x, lane = tid & 63, wid = tid >> 6;
  int q = lane & 31, h2 = lane >> 5;

  const char* Ksrc = (const char*)Kb + (size_t)g * 65536;
#pragma unroll
  for (int r = 0; r < 4; ++r) {
    int dk = tid * 16 + r * 16384;
    GLDS16(Ksrc + (dk ^ (((dk >> 7) & 7) << 4)), Ks + dk);
  }

  // V: k_vt-shape transpose from Vh[s][d] into swizzled Vs[d][s]
  {
    const unsigned short* VhG = Vh + g * 32768;
    int d = tid & 31, s8b = tid >> 5;
#pragma unroll
    for (int it = 0; it < 4; ++it) {
      int s8 = s8b + it * 32;
      us8 v;
#pragma unroll
      for (int i = 0; i < 8; ++i) v[i] = VhG[(s8 * 8 + i) * 32 + d];
      *(us8*)(Vs + ((d * 2048 + s8 * 16) ^ ((d & 7) << 4))) = v;
    }
  }

  const unsigned short* Qg = Qb + g * 32768 + wid * 2048;
  f16x8 qf[2][2];
#pragma unroll
  for (int qt = 0; qt < 2; ++qt)
#pragma unroll
    for (int kh = 0; kh < 2; ++kh)
      qf[qt][kh] = *(const f16x8*)&Qg[(qt * 32 + q) * 32 + kh * 16 + h2 * 8];

  int kbase = (q * 64 + h2 * 16) ^ (((q >> 1) & 7) << 4);
  int vbase = (q * 2048 + h2 * 16) ^ ((q & 7) << 4);

  const f16x2 ones2 = {(_Float16)1.0f, (_Float16)1.0f};
  f32x16 o[2];
#pragma unroll
  for (int i = 0; i < 16; ++i) { o[0][i] = 0.f; o[1][i] = 0.f; }
  float lacc[2] = {0.f, 0.f};
  f32x16 neg24;
#pragma unroll
  for (int i = 0; i < 16; ++i) neg24[i] = -24.f;

  __syncthreads();  // drains GLDS (vmcnt) + ds_writes (lgkm) for all waves

  f16x8 k0A, k1A, v0A, v1A, k0B, k1B, v0B, v1B;
  f32x16 stA, s1, s2, s3;
  LOADKF(0, 0, k0A, k1A);
  LOADVF(0, 0, v0A, v1A);
  QK2(stA, k0A, k1A, 0);

  for (int kv = 0; kv < 16; ++kv) {
    QK2(s1, k0A, k1A, 1);
    PROC(stA, 0, v0A, v1A);
    LOADKF(kv, 1, k0B, k1B);
    LOADVF(kv, 1, v0B, v1B);
    QK2(s2, k0B, k1B, 0);
    PROC(s1, 1, v0A, v1A);
    QK2(s3, k0B, k1B, 1);
    PROC(s2, 0, v0B, v1B);
    if (kv < 15) {
      LOADKF(kv + 1, 0, k0A, k1A);
      LOADVF(kv + 1, 0, v0A, v1A);
      QK2(stA, k0A, k1A, 0);
    }
    PROC(s3, 1, v0B, v1B);
  }

#pragma unroll
  for (int qt = 0; qt < 2; ++qt)
    lacc[qt] += __shfl_xor(lacc[qt], 32, 64);

#pragma unroll
  for (int qt = 0; qt < 2; ++qt) {
    float iv = 1.0f / lacc[qt];
    int rowoff = g * 32768 + (wid * 64 + qt * 32 + q) * 32;
#pragma unroll
    for (int rg = 0; rg < 4; ++rg) {
      int off = rowoff + rg * 8 + h2 * 4;   // d = (r&3) + 8*rg + 4*h2
      ushort4 rr = *(const ushort4*)&Rh[off];
      float4 ov;
      ov.x = fmaxf(h2f(rr.x) + o[qt][4 * rg + 0] * iv, 0.f);
      ov.y = fmaxf(h2f(rr.y) + o[qt][4 * rg + 1] * iv, 0.f);
      ov.z = fmaxf(h2f(rr.z) + o[qt][4 * rg + 2] * iv, 0.f);
      ov.w = fmaxf(h2f(rr.w) + o[qt][4 * rg + 3] * iv, 0.f);
      *(float4*)&out[off] = ov;
    }
  }
}

extern "C" void kernel_launch(void* const* d_in, const int* in_sizes, int n_in,
                              void* d_out, int out_size, void* d_ws, size_t ws_size,
                              hipStream_t stream) {
  const float* key0 = (const float*)d_in[0];
  const float* value0 = (const float*)d_in[1];
  const float* query0 = (const float*)d_in[2];
  const float* Wk = (const float*)d_in[3];
  const float* bk = (const float*)d_in[4];
  const float* Wv = (const float*)d_in[5];
  const float* bv = (const float*)d_in[6];
  const float* Wq = (const float*)d_in[7];
  const float* bq = (const float*)d_in[8];
  const float* Wr = (const float*)d_in[9];
  const float* br = (const float*)d_in[10];
  float* out = (float*)d_out;
  char* ws = (char*)d_ws;
  unsigned short* Kb = (unsigned short*)(ws);              // 16 MB f16 [16384,512]
  unsigned short* Vh = (unsigned short*)(ws + 16777216);   // 16 MB f16 [16384,512]
  unsigned short* Qb = (unsigned short*)(ws + 33554432);   // 16 MB f16 (pre-scaled)
  unsigned short* Rh = (unsigned short*)(ws + 50331648);   // 16 MB f16 [16384,512]
  unsigned short* WT = (unsigned short*)(ws + 92274688);   // 1 MB f16 [4][512][256]

  k_convert_w<<<dim3(2048), dim3(256), 0, stream>>>(Wk, Wv, Wq, Wr, WT);
  k_gemm<<<dim3(1024), dim3(512), 0, stream>>>(key0, value0, query0, WT,
                                               bk, bv, bq, br, Kb, Vh, Qb, Rh);
  k_attn<<<dim3(256), dim3(1024), 0, stream>>>(Kb, Vh, Qb, Rh, out);
}